// Round 5
// baseline (44.923 us; speedup 1.0000x reference)
//
#include <hip/hip_runtime.h>

// x,y: [B=8, T=2048, C=1024] fp32.
// -mean(einsum('itj,itl->ijl', x, y)) ==
//   -(1/(B*C*C)) * sum_{rows} rowsum(x_row) * rowsum(y_row)
//
// Single fused kernel: streaming rowsum-product partials (identical math to
// round 4, which ran at the HBM read floor in graph replay), block-level LDS
// reduce to one double, one f64 atomicAdd per block into d_ws, last block
// (ticket) writes the final scalar. Eliminates the second dispatch (~6 us).
#define N_C    1024
#define DENOM  (8.0 * 1024.0 * 1024.0)  // B*C*C

#define THREADS 1024
#define BLOCKS  512
#define WPB     (THREADS / 64)          // 16 waves/block
#define TOTAL_WAVES (BLOCKS * WPB)      // 8192 waves, 2 rows each

__global__ __launch_bounds__(THREADS)
void corr_fused(const float* __restrict__ x,
                const float* __restrict__ y,
                double* __restrict__ acc,          // d_ws + 0, zeroed per call
                unsigned int* __restrict__ ticket, // d_ws + 8, zeroed per call
                float* __restrict__ out) {
    const int lane = threadIdx.x & 63;
    const int w    = threadIdx.x >> 6;
    const int wave = blockIdx.x * WPB + w;          // 0..8191

    const size_t base = (size_t)(2 * wave) * N_C;   // 2 consecutive rows
    const float4* x0 = (const float4*)(x + base);
    const float4* y0 = (const float4*)(y + base);
    const float4* x1 = (const float4*)(x + base + N_C);
    const float4* y1 = (const float4*)(y + base + N_C);

    // Pure streaming: 16 coalesced float4 loads, vector adds, no shuffles.
    float4 ax = {0,0,0,0}, ay = {0,0,0,0}, bx = {0,0,0,0}, by = {0,0,0,0};
    #pragma unroll
    for (int k = 0; k < 4; ++k) {
        float4 vx0 = x0[lane + 64 * k];
        float4 vy0 = y0[lane + 64 * k];
        float4 vx1 = x1[lane + 64 * k];
        float4 vy1 = y1[lane + 64 * k];
        ax.x += vx0.x; ax.y += vx0.y; ax.z += vx0.z; ax.w += vx0.w;
        ay.x += vy0.x; ay.y += vy0.y; ay.z += vy0.z; ay.w += vy0.w;
        bx.x += vx1.x; bx.y += vx1.y; bx.z += vx1.z; bx.w += vx1.w;
        by.x += vy1.x; by.y += vy1.y; by.z += vy1.z; by.w += vy1.w;
    }
    float sx0 = (ax.x + ax.y) + (ax.z + ax.w);
    float sy0 = (ay.x + ay.y) + (ay.z + ay.w);
    float sx1 = (bx.x + bx.y) + (bx.z + bx.w);
    float sy1 = (by.x + by.y) + (by.z + by.w);

    // Four independent interleaved 64-lane butterflies (one latency tail).
    #pragma unroll
    for (int off = 32; off > 0; off >>= 1) {
        sx0 += __shfl_xor(sx0, off, 64);
        sy0 += __shfl_xor(sy0, off, 64);
        sx1 += __shfl_xor(sx1, off, 64);
        sy1 += __shfl_xor(sy1, off, 64);
    }

    // Block reduce: 16 wave partials (double) in LDS.
    __shared__ double sdata[WPB];
    if (lane == 0) sdata[w] = (double)sx0 * (double)sy0
                            + (double)sx1 * (double)sy1;
    __syncthreads();

    if (threadIdx.x == 0) {
        double bs = 0.0;
        #pragma unroll
        for (int i = 0; i < WPB; ++i) bs += sdata[i];
        atomicAdd(acc, bs);                    // device-scope f64 atomic
        __threadfence();                       // make it visible before ticket
        unsigned int t = atomicAdd(ticket, 1u);
        if (t == BLOCKS - 1) {
            // Last block: read the fully-accumulated sum coherently.
            double total = atomicAdd(acc, 0.0);
            out[0] = (float)(-total / DENOM);
        }
    }
}

extern "C" void kernel_launch(void* const* d_in, const int* in_sizes, int n_in,
                              void* d_out, int out_size, void* d_ws, size_t ws_size,
                              hipStream_t stream) {
    const float* x = (const float*)d_in[0];
    const float* y = (const float*)d_in[1];
    float* out = (float*)d_out;
    double* acc = (double*)d_ws;
    unsigned int* ticket = (unsigned int*)((char*)d_ws + 8);

    // Zero accumulator + ticket each call (graph-capturable memset node).
    hipMemsetAsync(d_ws, 0, 16, stream);
    corr_fused<<<BLOCKS, THREADS, 0, stream>>>(x, y, acc, ticket, out);
}

// Round 6
// 26.322 us; speedup vs baseline: 1.7067x; 1.7067x over previous
//
#include <hip/hip_runtime.h>

// x,y: [B=8, T=2048, C=1024] fp32.
// -mean(einsum('itj,itl->ijl', x, y)) ==
//   -(1/(B*C*C)) * sum_{rows} rowsum(x_row) * rowsum(y_row)
//
// Round-4 structure (best: 28.1 us) + cheaper tail:
//  - kernel 1: 2048 blocks x 256 thr (8192 waves, 2 rows/wave), pure
//    streaming float4 loads, all cross-lane work hoisted to wave end,
//    then a tiny 4-wave LDS fold -> ONE double partial per block (2048).
//  - kernel 2: a single 64-lane wave, 16 double2 loads/lane, one butterfly,
//    no barriers, no LDS tree.
#define N_C    1024
#define DENOM  (8.0 * 1024.0 * 1024.0)  // B*C*C

#define THREADS 256
#define BLOCKS  2048
#define WPB     (THREADS / 64)            // 4 waves/block

__global__ __launch_bounds__(THREADS)
void corr_partial(const float* __restrict__ x,
                  const float* __restrict__ y,
                  double* __restrict__ partials) {
    const int lane = threadIdx.x & 63;
    const int w    = threadIdx.x >> 6;
    const int wave = blockIdx.x * WPB + w;          // 0..8191

    const size_t base = (size_t)(2 * wave) * N_C;   // 2 consecutive rows
    const float4* x0 = (const float4*)(x + base);
    const float4* y0 = (const float4*)(y + base);
    const float4* x1 = (const float4*)(x + base + N_C);
    const float4* y1 = (const float4*)(y + base + N_C);

    // Pure streaming: 16 coalesced float4 loads, vector adds, no shuffles.
    float4 ax = {0,0,0,0}, ay = {0,0,0,0}, bx = {0,0,0,0}, by = {0,0,0,0};
    #pragma unroll
    for (int k = 0; k < 4; ++k) {
        float4 vx0 = x0[lane + 64 * k];
        float4 vy0 = y0[lane + 64 * k];
        float4 vx1 = x1[lane + 64 * k];
        float4 vy1 = y1[lane + 64 * k];
        ax.x += vx0.x; ax.y += vx0.y; ax.z += vx0.z; ax.w += vx0.w;
        ay.x += vy0.x; ay.y += vy0.y; ay.z += vy0.z; ay.w += vy0.w;
        bx.x += vx1.x; bx.y += vx1.y; bx.z += vx1.z; bx.w += vx1.w;
        by.x += vy1.x; by.y += vy1.y; by.z += vy1.z; by.w += vy1.w;
    }
    float sx0 = (ax.x + ax.y) + (ax.z + ax.w);
    float sy0 = (ay.x + ay.y) + (ay.z + ay.w);
    float sx1 = (bx.x + bx.y) + (bx.z + bx.w);
    float sy1 = (by.x + by.y) + (by.z + by.w);

    // Four independent interleaved 64-lane butterflies (one latency tail).
    #pragma unroll
    for (int off = 32; off > 0; off >>= 1) {
        sx0 += __shfl_xor(sx0, off, 64);
        sy0 += __shfl_xor(sy0, off, 64);
        sx1 += __shfl_xor(sx1, off, 64);
        sy1 += __shfl_xor(sy1, off, 64);
    }

    // Fold the block's 4 wave-partials: 32 B LDS, one cheap 4-wave barrier.
    __shared__ double sdata[WPB];
    if (lane == 0) sdata[w] = (double)sx0 * (double)sy0
                            + (double)sx1 * (double)sy1;
    __syncthreads();
    if (threadIdx.x == 0)
        partials[blockIdx.x] = (sdata[0] + sdata[1]) + (sdata[2] + sdata[3]);
}

__global__ __launch_bounds__(64)
void corr_final_reduce(const double* __restrict__ partials,
                       float* __restrict__ out) {
    const int lane = threadIdx.x;          // single wave, 64 lanes
    // 2048 doubles / 64 lanes = 32 doubles = 16 double2 loads per lane.
    const double2* p = (const double2*)partials;
    double acc = 0.0;
    #pragma unroll
    for (int k = 0; k < 16; ++k) {
        double2 v = p[lane + 64 * k];      // coalesced, all 16 in flight
        acc += v.x + v.y;
    }
    #pragma unroll
    for (int off = 32; off > 0; off >>= 1)
        acc += __shfl_xor(acc, off, 64);
    if (lane == 0) out[0] = (float)(-acc / DENOM);
}

extern "C" void kernel_launch(void* const* d_in, const int* in_sizes, int n_in,
                              void* d_out, int out_size, void* d_ws, size_t ws_size,
                              hipStream_t stream) {
    const float* x = (const float*)d_in[0];
    const float* y = (const float*)d_in[1];
    float* out = (float*)d_out;
    double* partials = (double*)d_ws;   // BLOCKS * 8 = 16 KiB scratch

    corr_partial<<<BLOCKS, THREADS, 0, stream>>>(x, y, partials);
    corr_final_reduce<<<1, 64, 0, stream>>>(partials, out);
}